// Round 10
// baseline (140.255 us; speedup 1.0000x reference)
//
#include <hip/hip_runtime.h>

// GraphSAGE layer: out = relu(h @ Ws^T + (scatter_mean(h,src,dst)) @ Wn^T + b)
// N=50000, E=800000, dim 128.
// R10: fuse gather+GEMM (R9 flat => gather is L2/L3-BW-bound, not occupancy;
//      attack traffic instead). Gather sums live in registers laid out as the
//      MFMA A-fragment (node=w*16+(lane&15), dims=(lane>>4)*8+32*ks), so the
//      12.8MB accb write + 12.8MB read + one dispatch disappear.
constexpr int N_NODES_C = 50000;
constexpr int N_EDGES_C = 800000;
constexpr int DIM_C     = 128;

constexpr int NBKT  = 196;    // (50000+255)>>8
constexpr int CAP   = 8192;   // bucket capacity; mean fill 4096, sd ~64
constexpr int NB_SCAT  = 196; // bucket-scatter blocks: 4096 edges each
constexpr int NB_WCAST = 2;   // W-cast blocks: one per matrix
constexpr int NB_CASTK = 391; // h-cast blocks: 1024 thr x 16 elems, guarded

constexpr int NSUB2    = 128;  // nodes per half-bucket (fused kernel)
constexpr int CAP_SUB2 = 4096; // half-bucket edge capacity; mean 2048, sd ~45

typedef __attribute__((ext_vector_type(8))) short short8;  // 8 bf16, 4 VGPRs
typedef __attribute__((ext_vector_type(4))) float f32x4;

// Workspace layout (bytes), ~32.1 MB used:
constexpr size_t OFF_HB   = 0;                                   // ushort[N][128]
constexpr size_t OFF_PK   = (size_t)N_NODES_C * DIM_C * 2;       // 12,800,000
constexpr size_t OFF_GC   = OFF_PK + (size_t)NBKT * CAP * 4;     // 19,222,528
constexpr size_t OFF_WB   = OFF_GC + 1024;                       // ushort[2][128][128]

// round-to-nearest-even f32 -> bf16 bits (finite inputs only)
static __device__ __forceinline__ ushort f2bf(float f) {
  unsigned u = __float_as_uint(f);
  return (ushort)((u + 0x7FFFu + ((u >> 16) & 1u)) >> 16);
}
static __device__ __forceinline__ unsigned pack2(float a, float b) {
  return (unsigned)f2bf(a) | ((unsigned)f2bf(b) << 16);
}

// --------------------------------------------------------------------------
// K_A: fused bucket scatter + cast(W) + cast(h), scatter blocks first.
// scatter: 4096 edges -> LDS hist over 196 buckets -> one global atomicAdd
//   per nonzero bin (bulk reserve, ~38k total) -> scatter ((dst&255)<<16)|src.
// --------------------------------------------------------------------------
__global__ __launch_bounds__(1024) void sage_cast_bucket(
    const float* __restrict__ h, ushort* __restrict__ hb,
    const float* __restrict__ Wself, const float* __restrict__ Wneigh,
    ushort* __restrict__ wb,
    const int* __restrict__ src, const int* __restrict__ dst,
    int* __restrict__ gcur, unsigned* __restrict__ packed)
{
  const int b = blockIdx.x;
  const int t = threadIdx.x;
  if (b >= NB_SCAT) {
    const float* sp;
    ushort* dp;
    size_t i;
    if (b < NB_SCAT + NB_WCAST) {
      int m = b - NB_SCAT;                    // 0: Wself, 1: Wneigh
      sp = m ? Wneigh : Wself;
      dp = wb + (size_t)m * DIM_C * DIM_C;
      i = (size_t)t * 16;                     // 1024*16 = 16384 exactly
    } else {
      int tid = (b - NB_SCAT - NB_WCAST) * 1024 + t;
      if (tid >= 400000) return;              // 400000*16 = 6.4M elems
      sp = h; dp = hb; i = (size_t)tid * 16;
    }
    float4 a0 = *reinterpret_cast<const float4*>(sp + i);
    float4 a1 = *reinterpret_cast<const float4*>(sp + i + 4);
    float4 a2 = *reinterpret_cast<const float4*>(sp + i + 8);
    float4 a3 = *reinterpret_cast<const float4*>(sp + i + 12);
    uint4 o0, o1;
    o0.x = pack2(a0.x, a0.y); o0.y = pack2(a0.z, a0.w);
    o0.z = pack2(a1.x, a1.y); o0.w = pack2(a1.z, a1.w);
    o1.x = pack2(a2.x, a2.y); o1.y = pack2(a2.z, a2.w);
    o1.z = pack2(a3.x, a3.y); o1.w = pack2(a3.z, a3.w);
    *reinterpret_cast<uint4*>(dp + i)     = o0;
    *reinterpret_cast<uint4*>(dp + i + 8) = o1;
    return;
  }

  __shared__ int bh[NBKT];     // per-bucket count
  __shared__ int bofs[NBKT];   // reserved base in bucket region
  __shared__ int bcur[NBKT];   // local cursor

  const int e = b * 4096 + t * 4;            // E%4==0: int4 valid when e<E

  if (t < NBKT) bh[t] = 0;
  __syncthreads();

  int4 d4, s4;
  bool live = (e < N_EDGES_C);
  if (live) {
    d4 = *reinterpret_cast<const int4*>(dst + e);
    s4 = *reinterpret_cast<const int4*>(src + e);
    atomicAdd(&bh[d4.x >> 8], 1);
    atomicAdd(&bh[d4.y >> 8], 1);
    atomicAdd(&bh[d4.z >> 8], 1);
    atomicAdd(&bh[d4.w >> 8], 1);
  }
  __syncthreads();

  if (t < NBKT) {
    bcur[t] = 0;
    bofs[t] = (bh[t] > 0) ? atomicAdd(&gcur[t], bh[t]) : 0;
  }
  __syncthreads();

  if (live) {
    int dd[4] = {d4.x, d4.y, d4.z, d4.w};
    int ss[4] = {s4.x, s4.y, s4.z, s4.w};
#pragma unroll
    for (int i = 0; i < 4; i++) {
      int bkt = dd[i] >> 8;
      int p = bofs[bkt] + atomicAdd(&bcur[bkt], 1);
      if (p < CAP)   // statistically unreachable; memory-safety guard
        packed[(size_t)bkt * CAP + p] =
            ((unsigned)(dd[i] & 255) << 16) | (unsigned)ss[i];
    }
  }
}

// --------------------------------------------------------------------------
// K_B: fused per-half-bucket counting sort + gather-mean + MFMA GEMM + relu.
// Block (bucket b, half s): node-ids rid in [s*128, s*128+128). 392 blocks x
// 512 thr (8 waves); LDS ~76 KB -> 2 blocks/CU (16 waves, = R8/R9 regime).
//   prologue: stage both W (bf16) + bias into LDS;
//   pass 1:   uint4 filtered scan of bucket run -> hist[128];
//   scan:     wave-0 shfl exclusive scan, 2 bins/lane;
//   pass 2:   filtered placement into esrc_l (LDS cursors);
//   gather:   lane (w,l): node rid=w*16+(l&15), dims (l>>4)*8+32*ks; sums in
//             registers == mean A-fragment layout; 1/deg from hist;
//   gemm:     K=256 (h A-frags from global, mean A-frags from registers),
//             C/D col=lane&15, row=q*4+reg (m89/m91-verified), bias+relu.
// --------------------------------------------------------------------------
__global__ __launch_bounds__(512, 4) void sage_sort_gather_gemm(
    const unsigned* __restrict__ packed, const int* __restrict__ gcur,
    const ushort* __restrict__ hb, const ushort* __restrict__ wb,
    const float* __restrict__ bias, float* __restrict__ out)
{
  __shared__ ushort Bl[DIM_C][256 + 8];   // 67,584 B
  __shared__ float  bias_l[DIM_C];
  __shared__ ushort esrc_l[CAP_SUB2];     //  8,192 B
  __shared__ int    hist[NSUB2];
  __shared__ int    excl_s[NSUB2];
  __shared__ int    curb[NSUB2];

  const int t    = threadIdx.x;
  const int b    = blockIdx.x >> 1;
  const int half = blockIdx.x & 1;
  const int rlo  = half * NSUB2;

  // Stage both W matrices (bf16, uint4 copies) + bias; zero hist.
  for (int idx = t; idx < DIM_C * 16; idx += 512) {
    int n  = idx >> 4;
    int c8 = (idx & 15) << 3;
    uint4 w0 = *reinterpret_cast<const uint4*>(wb + (size_t)n * DIM_C + c8);
    uint4 w1 = *reinterpret_cast<const uint4*>(wb + (size_t)(DIM_C + n) * DIM_C + c8);
    *reinterpret_cast<uint4*>(&Bl[n][c8])       = w0;
    *reinterpret_cast<uint4*>(&Bl[n][128 + c8]) = w1;
  }
  if (t < DIM_C) bias_l[t] = bias[t];
  if (t < NSUB2) hist[t] = 0;
  __syncthreads();

  const int count = min(gcur[b], CAP);
  const unsigned* pk = packed + (size_t)b * CAP;
  const int nvec  = count >> 2;
  const int ntail = count & 3;

  // pass 1: histogram of our rid range (vectorized, L2-hot)
  for (int g = t; g < nvec; g += 512) {
    uint4 w4 = *reinterpret_cast<const uint4*>(pk + g * 4);
    int r;
    r = (int)(w4.x >> 16) - rlo; if ((unsigned)r < (unsigned)NSUB2) atomicAdd(&hist[r], 1);
    r = (int)(w4.y >> 16) - rlo; if ((unsigned)r < (unsigned)NSUB2) atomicAdd(&hist[r], 1);
    r = (int)(w4.z >> 16) - rlo; if ((unsigned)r < (unsigned)NSUB2) atomicAdd(&hist[r], 1);
    r = (int)(w4.w >> 16) - rlo; if ((unsigned)r < (unsigned)NSUB2) atomicAdd(&hist[r], 1);
  }
  if (t < ntail) {
    int r = (int)(pk[nvec * 4 + t] >> 16) - rlo;
    if ((unsigned)r < (unsigned)NSUB2) atomicAdd(&hist[r], 1);
  }
  __syncthreads();

  // exclusive scan of hist[128] by wave 0, 2 bins per lane
  if (t < 64) {
    int v0 = hist[2 * t], v1 = hist[2 * t + 1];
    int s = v0 + v1;
    int x = s;
#pragma unroll
    for (int d = 1; d < 64; d <<= 1) {
      int y = __shfl_up(x, d, 64);
      if (t >= d) x += y;
    }
    int ex = x - s;
    excl_s[2 * t]     = ex;
    excl_s[2 * t + 1] = ex + v0;
    curb[2 * t]       = ex;
    curb[2 * t + 1]   = ex + v0;
  }
  __syncthreads();

  // pass 2: filtered placement
  for (int g = t; g < nvec; g += 512) {
    uint4 w4 = *reinterpret_cast<const uint4*>(pk + g * 4);
    unsigned ww[4] = {w4.x, w4.y, w4.z, w4.w};
#pragma unroll
    for (int j = 0; j < 4; j++) {
      int r = (int)(ww[j] >> 16) - rlo;
      if ((unsigned)r < (unsigned)NSUB2) {
        int p = atomicAdd(&curb[r], 1);
        if (p < CAP_SUB2) esrc_l[p] = (ushort)(ww[j] & 0xFFFFu);
      }
    }
  }
  if (t < ntail) {
    unsigned w = pk[nvec * 4 + t];
    int r = (int)(w >> 16) - rlo;
    if ((unsigned)r < (unsigned)NSUB2) {
      int p = atomicAdd(&curb[r], 1);
      if (p < CAP_SUB2) esrc_l[p] = (ushort)(w & 0xFFFFu);
    }
  }
  __syncthreads();

  // gather: lane (w,l) accumulates node rid = w*16+(l&15), dims q*8+32*ks.
  const int lane = t & 63;
  const int w    = t >> 6;
  const int am   = lane & 15;
  const int q    = lane >> 4;
  const int rid  = w * 16 + am;
  const int node = (b << 8) + rlo + rid;

  int begin = min(excl_s[rid], CAP_SUB2);
  int cnt   = hist[rid];
  int end   = min(begin + cnt, CAP_SUB2);

  float sums[4][8];
#pragma unroll
  for (int ks = 0; ks < 4; ks++)
#pragma unroll
    for (int j = 0; j < 8; j++) sums[ks][j] = 0.f;

#define ACCK(u, S)                                   \
  do {                                               \
    (S)[0] += __uint_as_float((u).x << 16);          \
    (S)[1] += __uint_as_float((u).x & 0xFFFF0000u);  \
    (S)[2] += __uint_as_float((u).y << 16);          \
    (S)[3] += __uint_as_float((u).y & 0xFFFF0000u);  \
    (S)[4] += __uint_as_float((u).z << 16);          \
    (S)[5] += __uint_as_float((u).z & 0xFFFF0000u);  \
    (S)[6] += __uint_as_float((u).w << 16);          \
    (S)[7] += __uint_as_float((u).w & 0xFFFF0000u);  \
  } while (0)

  int i = begin;
  for (; i + 1 < end; i += 2) {
    int e0 = esrc_l[i], e1 = esrc_l[i + 1];
    const ushort* r0 = hb + (size_t)e0 * DIM_C + q * 8;
    const ushort* r1 = hb + (size_t)e1 * DIM_C + q * 8;
#pragma unroll
    for (int ks = 0; ks < 4; ks++) {
      uint4 a = *reinterpret_cast<const uint4*>(r0 + ks * 32);
      uint4 c = *reinterpret_cast<const uint4*>(r1 + ks * 32);
      ACCK(a, sums[ks]);
      ACCK(c, sums[ks]);
    }
  }
  if (i < end) {
    int e0 = esrc_l[i];
    const ushort* r0 = hb + (size_t)e0 * DIM_C + q * 8;
#pragma unroll
    for (int ks = 0; ks < 4; ks++) {
      uint4 a = *reinterpret_cast<const uint4*>(r0 + ks * 32);
      ACCK(a, sums[ks]);
    }
  }
#undef ACCK

  // mean A-fragments in registers (bf16)
  const float id = 1.0f / (float)max(cnt, 1);   // == 1/deg[node]
  short8 afm[4];
#pragma unroll
  for (int ks = 0; ks < 4; ks++) {
    uint4 u;
    u.x = pack2(sums[ks][0] * id, sums[ks][1] * id);
    u.y = pack2(sums[ks][2] * id, sums[ks][3] * id);
    u.z = pack2(sums[ks][4] * id, sums[ks][5] * id);
    u.w = pack2(sums[ks][6] * id, sums[ks][7] * id);
    afm[ks] = *reinterpret_cast<short8*>(&u);
  }

  // GEMM: K=256. h self-term A-frags from global; mean A-frags from regs.
  int nclamp = (node < N_NODES_C) ? node : (N_NODES_C - 1);
  const ushort* aph = hb + (size_t)nclamp * DIM_C + q * 8;

  f32x4 acc[8];
#pragma unroll
  for (int nt = 0; nt < 8; nt++) acc[nt] = (f32x4){0.f, 0.f, 0.f, 0.f};

#pragma unroll
  for (int ks = 0; ks < 4; ks++) {
    short8 ah = *reinterpret_cast<const short8*>(aph + ks * 32);
#pragma unroll
    for (int nt = 0; nt < 8; nt++) {
      short8 bf = *reinterpret_cast<const short8*>(&Bl[nt * 16 + am][ks * 32 + q * 8]);
      acc[nt] = __builtin_amdgcn_mfma_f32_16x16x32_bf16(ah, bf, acc[nt], 0, 0, 0);
    }
  }
#pragma unroll
  for (int ks = 0; ks < 4; ks++) {
#pragma unroll
    for (int nt = 0; nt < 8; nt++) {
      short8 bf = *reinterpret_cast<const short8*>(&Bl[nt * 16 + am][128 + ks * 32 + q * 8]);
      acc[nt] = __builtin_amdgcn_mfma_f32_16x16x32_bf16(afm[ks], bf, acc[nt], 0, 0, 0);
    }
  }

  // epilogue: C/D row = tile_base + q*4 + rr, col = nt*16 + am
  const int rowbase = (b << 8) + rlo + w * 16;
#pragma unroll
  for (int nt = 0; nt < 8; nt++) {
    int col = nt * 16 + am;
    float bv = bias_l[col];
#pragma unroll
    for (int rr = 0; rr < 4; rr++) {
      int row = rowbase + q * 4 + rr;
      if (row < N_NODES_C) {
        float v = acc[nt][rr] + bv;
        out[(size_t)row * DIM_C + col] = fmaxf(v, 0.f);
      }
    }
  }
}

// --------------------------------------------------------------------------
extern "C" void kernel_launch(void* const* d_in, const int* in_sizes, int n_in,
                              void* d_out, int out_size, void* d_ws, size_t ws_size,
                              hipStream_t stream) {
  const float* h      = (const float*)d_in[0];
  const int*   src    = (const int*)d_in[1];
  const int*   dst    = (const int*)d_in[2];
  const float* Wself  = (const float*)d_in[4];
  const float* Wneigh = (const float*)d_in[5];
  const float* bias   = (const float*)d_in[6];
  float*       out    = (float*)d_out;

  char* ws = (char*)d_ws;
  ushort*   hb     = (ushort*)(ws + OFF_HB);
  unsigned* packed = (unsigned*)(ws + OFF_PK);
  int*      gcur   = (int*)(ws + OFF_GC);
  ushort*   wb     = (ushort*)(ws + OFF_WB);

  // Zero the 196 bucket cursors only (784 B); all else fully overwritten.
  hipMemsetAsync(gcur, 0, NBKT * sizeof(int), stream);

  sage_cast_bucket<<<NB_SCAT + NB_WCAST + NB_CASTK, 1024, 0, stream>>>(
      h, hb, Wself, Wneigh, wb, src, dst, gcur, packed);
  sage_sort_gather_gemm<<<NBKT * 2, 512, 0, stream>>>(packed, gcur, hb, wb,
                                                      bias, out);
}

// Round 11
// 138.013 us; speedup vs baseline: 1.0162x; 1.0162x over previous
//
#include <hip/hip_runtime.h>

// GraphSAGE layer: out = relu(h @ Ws^T + (scatter_mean(h,src,dst)) @ Wn^T + b)
// N=50000, E=800000, dim 128.
// R11: (a) revert to R9's split csr_gather+gemm (R10 fusion was neutral:
//      48.4us fused == sum of parts; A-frag gather mapping worsened
//      divergence to max-over-16 degrees); (b) scatter rebuilt: 8192
//      edges/block, LDS counting-sort, then per-run coalesced burst writes
//      (cast_bucket sat at ~40us since R4 on 800k scattered 4B stores ~ 5x
//      its 8us streaming cost). dur_us includes the harness's 268MB ws
//      poison (~43us fill rows) - immovable floor.
constexpr int N_NODES_C = 50000;
constexpr int N_EDGES_C = 800000;
constexpr int DIM_C     = 128;

constexpr int NBKT  = 196;    // (50000+255)>>8
constexpr int CAP   = 8192;   // bucket capacity; mean fill 4096, sd ~64
constexpr int EPB_S = 8192;   // edges per scatter block
constexpr int NB_SCAT  = 98;  // (800000+8191)/8192
constexpr int NB_WCAST = 2;   // W-cast blocks: one per matrix
constexpr int NB_CASTK = 391; // h-cast blocks: 1024 thr x 16 elems, guarded

constexpr int SUBS    = 4;    // csr_gather sub-blocks per bucket
constexpr int NSUB    = 64;   // nodes per sub-block
constexpr int CAP_SUB = 2048; // sub-block edge capacity; mean 1024, sd ~32

typedef __attribute__((ext_vector_type(8))) short short8;  // 8 bf16, 4 VGPRs
typedef __attribute__((ext_vector_type(4))) float f32x4;

// Workspace layout (bytes), ~32.2 MB used:
constexpr size_t OFF_HB   = 0;                                   // ushort[N][128]
constexpr size_t OFF_ACC  = (size_t)N_NODES_C * DIM_C * 2;       // 12,800,000
constexpr size_t OFF_PK   = OFF_ACC + (size_t)N_NODES_C * DIM_C * 2;  // 25,600,000
constexpr size_t OFF_GC   = OFF_PK + (size_t)NBKT * CAP * 4;     // 32,022,528
constexpr size_t OFF_WB   = OFF_GC + 1024;                       // ushort[2][128][128]

// round-to-nearest-even f32 -> bf16 bits (finite inputs only)
static __device__ __forceinline__ ushort f2bf(float f) {
  unsigned u = __float_as_uint(f);
  return (ushort)((u + 0x7FFFu + ((u >> 16) & 1u)) >> 16);
}
static __device__ __forceinline__ unsigned pack2(float a, float b) {
  return (unsigned)f2bf(a) | ((unsigned)f2bf(b) << 16);
}

// --------------------------------------------------------------------------
// K_A: fused bucket scatter + cast(W) + cast(h), scatter blocks first.
// Scatter block (8192 edges): LDS hist over 196 buckets -> wave-0 scan ->
// one global atomicAdd per nonzero bin (bulk reserve, ~19k total) -> LDS
// counting sort into sorted[8192] -> per-run coalesced burst write-out
// (wave w owns buckets w, w+16, ...; consecutive lanes, consecutive addrs).
// --------------------------------------------------------------------------
__global__ __launch_bounds__(1024) void sage_cast_bucket(
    const float* __restrict__ h, ushort* __restrict__ hb,
    const float* __restrict__ Wself, const float* __restrict__ Wneigh,
    ushort* __restrict__ wb,
    const int* __restrict__ src, const int* __restrict__ dst,
    int* __restrict__ gcur, unsigned* __restrict__ packed)
{
  const int b = blockIdx.x;
  const int t = threadIdx.x;
  if (b >= NB_SCAT) {
    const float* sp;
    ushort* dp;
    size_t i;
    if (b < NB_SCAT + NB_WCAST) {
      int m = b - NB_SCAT;                    // 0: Wself, 1: Wneigh
      sp = m ? Wneigh : Wself;
      dp = wb + (size_t)m * DIM_C * DIM_C;
      i = (size_t)t * 16;                     // 1024*16 = 16384 exactly
    } else {
      int tid = (b - NB_SCAT - NB_WCAST) * 1024 + t;
      if (tid >= 400000) return;              // 400000*16 = 6.4M elems
      sp = h; dp = hb; i = (size_t)tid * 16;
    }
    float4 a0 = *reinterpret_cast<const float4*>(sp + i);
    float4 a1 = *reinterpret_cast<const float4*>(sp + i + 4);
    float4 a2 = *reinterpret_cast<const float4*>(sp + i + 8);
    float4 a3 = *reinterpret_cast<const float4*>(sp + i + 12);
    uint4 o0, o1;
    o0.x = pack2(a0.x, a0.y); o0.y = pack2(a0.z, a0.w);
    o0.z = pack2(a1.x, a1.y); o0.w = pack2(a1.z, a1.w);
    o1.x = pack2(a2.x, a2.y); o1.y = pack2(a2.z, a2.w);
    o1.z = pack2(a3.x, a3.y); o1.w = pack2(a3.z, a3.w);
    *reinterpret_cast<uint4*>(dp + i)     = o0;
    *reinterpret_cast<uint4*>(dp + i + 8) = o1;
    return;
  }

  __shared__ int      bh[256];       // per-bucket count (padded for scan)
  __shared__ int      excl[256];
  __shared__ int      curb[NBKT];
  __shared__ int      bofsG[NBKT];   // reserved base within bucket region
  __shared__ unsigned sorted[EPB_S]; // 32 KB

  const int e0 = b * EPB_S + t * 8;
  const bool l0 = (e0     < N_EDGES_C);      // E%4==0: int4 valid when base<E
  const bool l1 = (e0 + 4 < N_EDGES_C);

  if (t < 256) bh[t] = 0;
  __syncthreads();

  int4 da, db, sa, sb;
  if (l0) {
    da = *reinterpret_cast<const int4*>(dst + e0);
    sa = *reinterpret_cast<const int4*>(src + e0);
    atomicAdd(&bh[da.x >> 8], 1); atomicAdd(&bh[da.y >> 8], 1);
    atomicAdd(&bh[da.z >> 8], 1); atomicAdd(&bh[da.w >> 8], 1);
  }
  if (l1) {
    db = *reinterpret_cast<const int4*>(dst + e0 + 4);
    sb = *reinterpret_cast<const int4*>(src + e0 + 4);
    atomicAdd(&bh[db.x >> 8], 1); atomicAdd(&bh[db.y >> 8], 1);
    atomicAdd(&bh[db.z >> 8], 1); atomicAdd(&bh[db.w >> 8], 1);
  }
  __syncthreads();

  // exclusive scan of bh[256] by wave 0 (4 bins/lane)
  if (t < 64) {
    int base = t * 4;
    int h0 = bh[base], h1 = bh[base + 1], h2 = bh[base + 2], h3 = bh[base + 3];
    int s = h0 + h1 + h2 + h3;
    int x = s;
#pragma unroll
    for (int d = 1; d < 64; d <<= 1) {
      int y = __shfl_up(x, d, 64);
      if (t >= d) x += y;
    }
    int ex = x - s;
    excl[base]     = ex;
    excl[base + 1] = ex + h0;
    excl[base + 2] = ex + h0 + h1;
    excl[base + 3] = ex + h0 + h1 + h2;
  }
  __syncthreads();

  if (t < NBKT) {
    curb[t]  = excl[t];
    bofsG[t] = (bh[t] > 0) ? atomicAdd(&gcur[t], bh[t]) : 0;
  }
  __syncthreads();

  // counting-sort the block's edges into LDS (by bucket)
#define PLACE(dd, ss)                                            \
  do {                                                           \
    int p_ = atomicAdd(&curb[(dd) >> 8], 1);                     \
    sorted[p_] = ((unsigned)((dd) & 255) << 16) | (unsigned)(ss);\
  } while (0)
  if (l0) { PLACE(da.x, sa.x); PLACE(da.y, sa.y); PLACE(da.z, sa.z); PLACE(da.w, sa.w); }
  if (l1) { PLACE(db.x, sb.x); PLACE(db.y, sb.y); PLACE(db.z, sb.z); PLACE(db.w, sb.w); }
#undef PLACE
  __syncthreads();

  // coalesced burst write-out: wave w owns buckets w, w+16, ...
  const int w    = t >> 6;
  const int lane = t & 63;
  for (int k = w; k < NBKT; k += 16) {
    int len = bh[k];
    int gb  = bofsG[k];
    if (gb + len > CAP) len = CAP - gb;      // statistically unreachable
    int lb  = excl[k];
    unsigned* outp = packed + (size_t)k * CAP + gb;
    for (int off = lane; off < len; off += 64)
      outp[off] = sorted[lb + off];
  }
}

// --------------------------------------------------------------------------
// K_B: per-sub-bucket counting sort + gather-mean (R9, measured-best).
// Block (bucket b, sub s) owns node-ids rid in [s*64, s*64+64). 784x256.
// --------------------------------------------------------------------------
__global__ __launch_bounds__(256) void sage_csr_gather(
    const unsigned* __restrict__ packed, const int* __restrict__ gcur,
    const ushort* __restrict__ hb, ushort* __restrict__ accb)
{
  __shared__ int    hist[NSUB];
  __shared__ int    excl_s[NSUB];
  __shared__ int    curb[NSUB];
  __shared__ ushort esrc_l[CAP_SUB];   // 4 KB

  const int b   = blockIdx.x >> 2;     // bucket
  const int sub = blockIdx.x & 3;
  const int rlo = sub * NSUB;
  const int t = threadIdx.x;
  const int count = min(gcur[b], CAP);
  const unsigned* pk = packed + (size_t)b * CAP;
  const int nvec = count >> 2;
  const int ntail = count & 3;

  if (t < NSUB) hist[t] = 0;
  __syncthreads();

  // pass 1: histogram of our rid range (vectorized scan, L2-hot)
  for (int g = t; g < nvec; g += 256) {
    uint4 w4 = *reinterpret_cast<const uint4*>(pk + g * 4);
    int r;
    r = (int)(w4.x >> 16) - rlo; if ((unsigned)r < (unsigned)NSUB) atomicAdd(&hist[r], 1);
    r = (int)(w4.y >> 16) - rlo; if ((unsigned)r < (unsigned)NSUB) atomicAdd(&hist[r], 1);
    r = (int)(w4.z >> 16) - rlo; if ((unsigned)r < (unsigned)NSUB) atomicAdd(&hist[r], 1);
    r = (int)(w4.w >> 16) - rlo; if ((unsigned)r < (unsigned)NSUB) atomicAdd(&hist[r], 1);
  }
  if (t < ntail) {
    int r = (int)(pk[nvec * 4 + t] >> 16) - rlo;
    if ((unsigned)r < (unsigned)NSUB) atomicAdd(&hist[r], 1);
  }
  __syncthreads();

  // exclusive scan of hist[64] by wave 0 (1 bin per lane)
  if (t < 64) {
    int v = hist[t];
    int x = v;
#pragma unroll
    for (int d = 1; d < 64; d <<= 1) {
      int y = __shfl_up(x, d, 64);
      if (t >= d) x += y;
    }
    excl_s[t] = x - v;
    curb[t]   = x - v;
  }
  __syncthreads();

  // pass 2: filtered placement
  for (int g = t; g < nvec; g += 256) {
    uint4 w4 = *reinterpret_cast<const uint4*>(pk + g * 4);
    unsigned ww[4] = {w4.x, w4.y, w4.z, w4.w};
#pragma unroll
    for (int j = 0; j < 4; j++) {
      int r = (int)(ww[j] >> 16) - rlo;
      if ((unsigned)r < (unsigned)NSUB) {
        int p = atomicAdd(&curb[r], 1);
        esrc_l[p] = (ushort)(ww[j] & 0xFFFFu);
      }
    }
  }
  if (t < ntail) {
    unsigned w = pk[nvec * 4 + t];
    int r = (int)(w >> 16) - rlo;
    if ((unsigned)r < (unsigned)NSUB) {
      int p = atomicAdd(&curb[r], 1);
      esrc_l[p] = (ushort)(w & 0xFFFFu);
    }
  }
  __syncthreads();

  // gather: 4 rounds x 16 nodes; 16 lanes per node, 8 bf16 per lane.
  const int c = (t & 15) << 3;
#pragma unroll
  for (int rd = 0; rd < 4; rd++) {
    int lr = rd * 16 + (t >> 4);     // local rid 0..63
    int n = (b << 8) + rlo + lr;
    if (n >= N_NODES_C) continue;
    int begin = excl_s[lr];
    int cnt   = hist[lr];
    int end   = begin + cnt;

    float s0 = 0.f, s1 = 0.f, s2 = 0.f, s3 = 0.f;
    float s4 = 0.f, s5 = 0.f, s6 = 0.f, s7 = 0.f;

#define ACC8(u)                                                  \
    do {                                                         \
      s0 += __uint_as_float((u).x << 16);                        \
      s1 += __uint_as_float((u).x & 0xFFFF0000u);                \
      s2 += __uint_as_float((u).y << 16);                        \
      s3 += __uint_as_float((u).y & 0xFFFF0000u);                \
      s4 += __uint_as_float((u).z << 16);                        \
      s5 += __uint_as_float((u).z & 0xFFFF0000u);                \
      s6 += __uint_as_float((u).w << 16);                        \
      s7 += __uint_as_float((u).w & 0xFFFF0000u);                \
    } while (0)

    int i = begin;
    for (; i + 3 < end; i += 4) {
      int e0 = esrc_l[i], e1 = esrc_l[i + 1], e2 = esrc_l[i + 2], e3 = esrc_l[i + 3];
      uint4 a  = *reinterpret_cast<const uint4*>(hb + (size_t)e0 * DIM_C + c);
      uint4 bb = *reinterpret_cast<const uint4*>(hb + (size_t)e1 * DIM_C + c);
      uint4 d  = *reinterpret_cast<const uint4*>(hb + (size_t)e2 * DIM_C + c);
      uint4 f  = *reinterpret_cast<const uint4*>(hb + (size_t)e3 * DIM_C + c);
      ACC8(a); ACC8(bb); ACC8(d); ACC8(f);
    }
    for (; i < end; i++) {
      int e0 = esrc_l[i];
      uint4 a = *reinterpret_cast<const uint4*>(hb + (size_t)e0 * DIM_C + c);
      ACC8(a);
    }
#undef ACC8

    float id = 1.0f / (float)max(cnt, 1);   // == 1/deg[n] by construction
    uint4 o;
    o.x = pack2(s0 * id, s1 * id);
    o.y = pack2(s2 * id, s3 * id);
    o.z = pack2(s4 * id, s5 * id);
    o.w = pack2(s6 * id, s7 * id);
    *reinterpret_cast<uint4*>(accb + (size_t)n * DIM_C + c) = o;
  }
}

// --------------------------------------------------------------------------
// K4: fused bf16 MFMA GEMM, K=256 (k<128 from h_bf16, k>=128 from acc_bf16).
// Block = 256 thr (4 waves), 128 rows/block. W staged from pre-cast bf16
// global into padded LDS (uint4 copies).
// Layouts (m89/m91-verified): A[m=lane&15][k=quad*8+j];
// B from W[n][k] with n=lane&15, k=quad*8+j; C/D col=lane&15, row=quad*4+reg.
// --------------------------------------------------------------------------
__global__ __launch_bounds__(256) void sage_gemm_mfma(
    const ushort* __restrict__ hb, const ushort* __restrict__ accb,
    const ushort* __restrict__ wb, const float* __restrict__ bias,
    float* __restrict__ out)
{
  __shared__ ushort Bl[DIM_C][256 + 8];   // 67,584 B
  __shared__ float  bias_l[DIM_C];

  const int t = threadIdx.x;

  for (int idx = t; idx < DIM_C * 16; idx += 256) {
    int n  = idx >> 4;
    int c8 = (idx & 15) << 3;
    uint4 w0 = *reinterpret_cast<const uint4*>(wb + (size_t)n * DIM_C + c8);
    uint4 w1 = *reinterpret_cast<const uint4*>(wb + (size_t)(DIM_C + n) * DIM_C + c8);
    *reinterpret_cast<uint4*>(&Bl[n][c8])       = w0;
    *reinterpret_cast<uint4*>(&Bl[n][128 + c8]) = w1;
  }
  if (t < DIM_C) bias_l[t] = bias[t];
  __syncthreads();

  const int lane = t & 63;
  const int w    = t >> 6;
  const int am   = lane & 15;
  const int q    = lane >> 4;
  const int mb   = blockIdx.x * 128;
  const int m0   = mb + w * 16;        // row-tile 0
  const int m1   = mb + 64 + w * 16;   // row-tile 1

  int r0 = m0 + am; if (r0 >= N_NODES_C) r0 = N_NODES_C - 1;
  int r1 = m1 + am; if (r1 >= N_NODES_C) r1 = N_NODES_C - 1;
  const ushort* aph0 = hb   + (size_t)r0 * DIM_C + q * 8;
  const ushort* apa0 = accb + (size_t)r0 * DIM_C + q * 8;
  const ushort* aph1 = hb   + (size_t)r1 * DIM_C + q * 8;
  const ushort* apa1 = accb + (size_t)r1 * DIM_C + q * 8;

  f32x4 acc[2][8];
#pragma unroll
  for (int i = 0; i < 2; i++)
#pragma unroll
    for (int nt = 0; nt < 8; nt++) acc[i][nt] = (f32x4){0.f, 0.f, 0.f, 0.f};

#pragma unroll
  for (int ks = 0; ks < 4; ks++) {
    short8 a0 = *reinterpret_cast<const short8*>(aph0 + ks * 32);
    short8 a1 = *reinterpret_cast<const short8*>(aph1 + ks * 32);
#pragma unroll
    for (int nt = 0; nt < 8; nt++) {
      short8 bf = *reinterpret_cast<const short8*>(&Bl[nt * 16 + am][ks * 32 + q * 8]);
      acc[0][nt] = __builtin_amdgcn_mfma_f32_16x16x32_bf16(a0, bf, acc[0][nt], 0, 0, 0);
      acc[1][nt] = __builtin_amdgcn_mfma_f32_16x16x32_bf16(a1, bf, acc[1][nt], 0, 0, 0);
    }
  }
#pragma unroll
  for (int ks = 0; ks < 4; ks++) {
    short8 a0 = *reinterpret_cast<const short8*>(apa0 + ks * 32);
    short8 a1 = *reinterpret_cast<const short8*>(apa1 + ks * 32);
#pragma unroll
    for (int nt = 0; nt < 8; nt++) {
      short8 bf = *reinterpret_cast<const short8*>(&Bl[nt * 16 + am][128 + ks * 32 + q * 8]);
      acc[0][nt] = __builtin_amdgcn_mfma_f32_16x16x32_bf16(a0, bf, acc[0][nt], 0, 0, 0);
      acc[1][nt] = __builtin_amdgcn_mfma_f32_16x16x32_bf16(a1, bf, acc[1][nt], 0, 0, 0);
    }
  }

#pragma unroll
  for (int i = 0; i < 2; i++) {
    int mt = (i == 0) ? m0 : m1;
#pragma unroll
    for (int nt = 0; nt < 8; nt++) {
      int col = nt * 16 + am;
      float bv = bias_l[col];
#pragma unroll
      for (int rr = 0; rr < 4; rr++) {
        int row = mt + q * 4 + rr;
        if (row < N_NODES_C) {
          float v = acc[i][nt][rr] + bv;
          out[(size_t)row * DIM_C + col] = fmaxf(v, 0.f);
        }
      }
    }
  }
}

// --------------------------------------------------------------------------
extern "C" void kernel_launch(void* const* d_in, const int* in_sizes, int n_in,
                              void* d_out, int out_size, void* d_ws, size_t ws_size,
                              hipStream_t stream) {
  const float* h      = (const float*)d_in[0];
  const int*   src    = (const int*)d_in[1];
  const int*   dst    = (const int*)d_in[2];
  const float* Wself  = (const float*)d_in[4];
  const float* Wneigh = (const float*)d_in[5];
  const float* bias   = (const float*)d_in[6];
  float*       out    = (float*)d_out;

  char* ws = (char*)d_ws;
  ushort*   hb     = (ushort*)(ws + OFF_HB);
  ushort*   accb   = (ushort*)(ws + OFF_ACC);
  unsigned* packed = (unsigned*)(ws + OFF_PK);
  int*      gcur   = (int*)(ws + OFF_GC);
  ushort*   wb     = (ushort*)(ws + OFF_WB);

  // Zero the 196 bucket cursors only (784 B); all else fully overwritten.
  hipMemsetAsync(gcur, 0, NBKT * sizeof(int), stream);

  sage_cast_bucket<<<NB_SCAT + NB_WCAST + NB_CASTK, 1024, 0, stream>>>(
      h, hb, Wself, Wneigh, wb, src, dst, gcur, packed);
  sage_csr_gather <<<NBKT * SUBS, 256, 0, stream>>>(packed, gcur, hb, accb);
  sage_gemm_mfma  <<<(N_NODES_C + 127) / 128, 256, 0, stream>>>(hb, accb, wb,
                                                                bias, out);
}

// Round 12
// 134.264 us; speedup vs baseline: 1.0446x; 1.0279x over previous
//
#include <hip/hip_runtime.h>

// GraphSAGE layer: out = relu(h @ Ws^T + (scatter_mean(h,src,dst)) @ Wn^T + b)
// N=50000, E=800000, dim 128.
// R12: fp8(e4m3) gather path. R10 counters: gather complex 48.4us with 80MB
//      FETCH (beyond-L2) at ~2TB/s, insensitive to occupancy (R9) and store
//      pattern (R11) => bytes/row is the only lever. Gather reads 128B fp8
//      rows (HW cvt), f32 accumulate, bf16 mean out. GEMM self-term stays
//      bf16 (fp8 there would exceed the error budget).
constexpr int N_NODES_C = 50000;
constexpr int N_EDGES_C = 800000;
constexpr int DIM_C     = 128;

constexpr int NBKT  = 196;    // (50000+255)>>8
constexpr int CAP   = 8192;   // bucket capacity; mean fill 4096, sd ~64
constexpr int EPB_S = 8192;   // edges per scatter block
constexpr int NB_SCAT  = 98;  // (800000+8191)/8192
constexpr int NB_WCAST = 2;   // W-cast blocks: one per matrix
constexpr int NB_CASTK = 391; // h-cast blocks: 1024 thr x 16 elems, guarded

constexpr int SUBS    = 4;    // csr_gather sub-blocks per bucket
constexpr int NSUB    = 64;   // nodes per sub-block
constexpr int CAP_SUB = 2048; // sub-block edge capacity; mean 1024, sd ~32

typedef __attribute__((ext_vector_type(8))) short short8;  // 8 bf16, 4 VGPRs
typedef __attribute__((ext_vector_type(4))) float f32x4;
typedef __attribute__((ext_vector_type(2))) float f32x2;

// Workspace layout (bytes), ~38.7 MB used:
constexpr size_t OFF_HB   = 0;                                   // ushort[N][128]
constexpr size_t OFF_ACC  = (size_t)N_NODES_C * DIM_C * 2;       // 12,800,000
constexpr size_t OFF_PK   = OFF_ACC + (size_t)N_NODES_C * DIM_C * 2;  // 25,600,000
constexpr size_t OFF_GC   = OFF_PK + (size_t)NBKT * CAP * 4;     // 32,022,528
constexpr size_t OFF_WB   = OFF_GC + 1024;                       // ushort[2][128][128]
constexpr size_t OFF_H8   = OFF_WB + 2 * DIM_C * DIM_C * 2;      // uchar[N][128] fp8

// round-to-nearest-even f32 -> bf16 bits (finite inputs only)
static __device__ __forceinline__ ushort f2bf(float f) {
  unsigned u = __float_as_uint(f);
  return (ushort)((u + 0x7FFFu + ((u >> 16) & 1u)) >> 16);
}
static __device__ __forceinline__ unsigned pack2(float a, float b) {
  return (unsigned)f2bf(a) | ((unsigned)f2bf(b) << 16);
}
// 4 floats -> 4 packed OCP e4m3 bytes (HW cvt, RNE)
static __device__ __forceinline__ unsigned pk_fp8x4(float4 a) {
  unsigned u = __builtin_amdgcn_cvt_pk_fp8_f32(a.x, a.y, 0u, false);
  return __builtin_amdgcn_cvt_pk_fp8_f32(a.z, a.w, u, true);
}

// --------------------------------------------------------------------------
// K_A: fused bucket scatter + cast(W) + cast(h -> bf16 AND fp8).
// Scatter block (8192 edges): LDS hist over 196 buckets -> wave-0 scan ->
// one global atomicAdd per nonzero bin (bulk reserve, ~19k total) -> LDS
// counting sort -> per-run coalesced burst write-out.
// --------------------------------------------------------------------------
__global__ __launch_bounds__(1024) void sage_cast_bucket(
    const float* __restrict__ h, ushort* __restrict__ hb,
    unsigned char* __restrict__ h8,
    const float* __restrict__ Wself, const float* __restrict__ Wneigh,
    ushort* __restrict__ wb,
    const int* __restrict__ src, const int* __restrict__ dst,
    int* __restrict__ gcur, unsigned* __restrict__ packed)
{
  const int b = blockIdx.x;
  const int t = threadIdx.x;
  if (b >= NB_SCAT) {
    if (b < NB_SCAT + NB_WCAST) {
      int m = b - NB_SCAT;                    // 0: Wself, 1: Wneigh
      const float* sp = m ? Wneigh : Wself;
      ushort* dp = wb + (size_t)m * DIM_C * DIM_C;
      size_t i = (size_t)t * 16;              // 1024*16 = 16384 exactly
      float4 a0 = *reinterpret_cast<const float4*>(sp + i);
      float4 a1 = *reinterpret_cast<const float4*>(sp + i + 4);
      float4 a2 = *reinterpret_cast<const float4*>(sp + i + 8);
      float4 a3 = *reinterpret_cast<const float4*>(sp + i + 12);
      uint4 o0, o1;
      o0.x = pack2(a0.x, a0.y); o0.y = pack2(a0.z, a0.w);
      o0.z = pack2(a1.x, a1.y); o0.w = pack2(a1.z, a1.w);
      o1.x = pack2(a2.x, a2.y); o1.y = pack2(a2.z, a2.w);
      o1.z = pack2(a3.x, a3.y); o1.w = pack2(a3.z, a3.w);
      *reinterpret_cast<uint4*>(dp + i)     = o0;
      *reinterpret_cast<uint4*>(dp + i + 8) = o1;
    } else {
      int tid = (b - NB_SCAT - NB_WCAST) * 1024 + t;
      if (tid >= 400000) return;              // 400000*16 = 6.4M elems
      size_t i = (size_t)tid * 16;
      float4 a0 = *reinterpret_cast<const float4*>(h + i);
      float4 a1 = *reinterpret_cast<const float4*>(h + i + 4);
      float4 a2 = *reinterpret_cast<const float4*>(h + i + 8);
      float4 a3 = *reinterpret_cast<const float4*>(h + i + 12);
      uint4 o0, o1;
      o0.x = pack2(a0.x, a0.y); o0.y = pack2(a0.z, a0.w);
      o0.z = pack2(a1.x, a1.y); o0.w = pack2(a1.z, a1.w);
      o1.x = pack2(a2.x, a2.y); o1.y = pack2(a2.z, a2.w);
      o1.z = pack2(a3.x, a3.y); o1.w = pack2(a3.z, a3.w);
      *reinterpret_cast<uint4*>(hb + i)     = o0;
      *reinterpret_cast<uint4*>(hb + i + 8) = o1;
      uint4 q;                                 // 16 fp8 bytes
      q.x = pk_fp8x4(a0); q.y = pk_fp8x4(a1);
      q.z = pk_fp8x4(a2); q.w = pk_fp8x4(a3);
      *reinterpret_cast<uint4*>(h8 + i) = q;
    }
    return;
  }

  __shared__ int      bh[256];       // per-bucket count (padded for scan)
  __shared__ int      excl[256];
  __shared__ int      curb[NBKT];
  __shared__ int      bofsG[NBKT];   // reserved base within bucket region
  __shared__ unsigned sorted[EPB_S]; // 32 KB

  const int e0 = b * EPB_S + t * 8;
  const bool l0 = (e0     < N_EDGES_C);      // E%4==0: int4 valid when base<E
  const bool l1 = (e0 + 4 < N_EDGES_C);

  if (t < 256) bh[t] = 0;
  __syncthreads();

  int4 da, db, sa, sb;
  if (l0) {
    da = *reinterpret_cast<const int4*>(dst + e0);
    sa = *reinterpret_cast<const int4*>(src + e0);
    atomicAdd(&bh[da.x >> 8], 1); atomicAdd(&bh[da.y >> 8], 1);
    atomicAdd(&bh[da.z >> 8], 1); atomicAdd(&bh[da.w >> 8], 1);
  }
  if (l1) {
    db = *reinterpret_cast<const int4*>(dst + e0 + 4);
    sb = *reinterpret_cast<const int4*>(src + e0 + 4);
    atomicAdd(&bh[db.x >> 8], 1); atomicAdd(&bh[db.y >> 8], 1);
    atomicAdd(&bh[db.z >> 8], 1); atomicAdd(&bh[db.w >> 8], 1);
  }
  __syncthreads();

  // exclusive scan of bh[256] by wave 0 (4 bins/lane)
  if (t < 64) {
    int base = t * 4;
    int h0 = bh[base], h1 = bh[base + 1], h2 = bh[base + 2], h3 = bh[base + 3];
    int s = h0 + h1 + h2 + h3;
    int x = s;
#pragma unroll
    for (int d = 1; d < 64; d <<= 1) {
      int y = __shfl_up(x, d, 64);
      if (t >= d) x += y;
    }
    int ex = x - s;
    excl[base]     = ex;
    excl[base + 1] = ex + h0;
    excl[base + 2] = ex + h0 + h1;
    excl[base + 3] = ex + h0 + h1 + h2;
  }
  __syncthreads();

  if (t < NBKT) {
    curb[t]  = excl[t];
    bofsG[t] = (bh[t] > 0) ? atomicAdd(&gcur[t], bh[t]) : 0;
  }
  __syncthreads();

#define PLACE(dd, ss)                                            \
  do {                                                           \
    int p_ = atomicAdd(&curb[(dd) >> 8], 1);                     \
    sorted[p_] = ((unsigned)((dd) & 255) << 16) | (unsigned)(ss);\
  } while (0)
  if (l0) { PLACE(da.x, sa.x); PLACE(da.y, sa.y); PLACE(da.z, sa.z); PLACE(da.w, sa.w); }
  if (l1) { PLACE(db.x, sb.x); PLACE(db.y, sb.y); PLACE(db.z, sb.z); PLACE(db.w, sb.w); }
#undef PLACE
  __syncthreads();

  // coalesced burst write-out: wave w owns buckets w, w+16, ...
  const int w    = t >> 6;
  const int lane = t & 63;
  for (int k = w; k < NBKT; k += 16) {
    int len = bh[k];
    int gb  = bofsG[k];
    if (gb + len > CAP) len = CAP - gb;      // statistically unreachable
    int lb  = excl[k];
    unsigned* outp = packed + (size_t)k * CAP + gb;
    for (int off = lane; off < len; off += 64)
      outp[off] = sorted[lb + off];
  }
}

// --------------------------------------------------------------------------
// K_B: per-sub-bucket counting sort + gather-mean, fp8 rows (128B/row).
// Block (bucket b, sub s) owns node-ids rid in [s*64, s*64+64). 784x256.
// 16 lanes/node x 8 fp8 (uint2) per lane; f32 accumulate via HW cvt;
// bf16 mean out. 1/deg from hist (== input deg by construction).
// --------------------------------------------------------------------------
__global__ __launch_bounds__(256) void sage_csr_gather(
    const unsigned* __restrict__ packed, const int* __restrict__ gcur,
    const unsigned char* __restrict__ h8, ushort* __restrict__ accb)
{
  __shared__ int    hist[NSUB];
  __shared__ int    excl_s[NSUB];
  __shared__ int    curb[NSUB];
  __shared__ ushort esrc_l[CAP_SUB];   // 4 KB

  const int b   = blockIdx.x >> 2;     // bucket
  const int sub = blockIdx.x & 3;
  const int rlo = sub * NSUB;
  const int t = threadIdx.x;
  const int count = min(gcur[b], CAP);
  const unsigned* pk = packed + (size_t)b * CAP;
  const int nvec = count >> 2;
  const int ntail = count & 3;

  if (t < NSUB) hist[t] = 0;
  __syncthreads();

  // pass 1: histogram of our rid range (vectorized scan, L2-hot)
  for (int g = t; g < nvec; g += 256) {
    uint4 w4 = *reinterpret_cast<const uint4*>(pk + g * 4);
    int r;
    r = (int)(w4.x >> 16) - rlo; if ((unsigned)r < (unsigned)NSUB) atomicAdd(&hist[r], 1);
    r = (int)(w4.y >> 16) - rlo; if ((unsigned)r < (unsigned)NSUB) atomicAdd(&hist[r], 1);
    r = (int)(w4.z >> 16) - rlo; if ((unsigned)r < (unsigned)NSUB) atomicAdd(&hist[r], 1);
    r = (int)(w4.w >> 16) - rlo; if ((unsigned)r < (unsigned)NSUB) atomicAdd(&hist[r], 1);
  }
  if (t < ntail) {
    int r = (int)(pk[nvec * 4 + t] >> 16) - rlo;
    if ((unsigned)r < (unsigned)NSUB) atomicAdd(&hist[r], 1);
  }
  __syncthreads();

  // exclusive scan of hist[64] by wave 0 (1 bin per lane)
  if (t < 64) {
    int v = hist[t];
    int x = v;
#pragma unroll
    for (int d = 1; d < 64; d <<= 1) {
      int y = __shfl_up(x, d, 64);
      if (t >= d) x += y;
    }
    excl_s[t] = x - v;
    curb[t]   = x - v;
  }
  __syncthreads();

  // pass 2: filtered placement
  for (int g = t; g < nvec; g += 256) {
    uint4 w4 = *reinterpret_cast<const uint4*>(pk + g * 4);
    unsigned ww[4] = {w4.x, w4.y, w4.z, w4.w};
#pragma unroll
    for (int j = 0; j < 4; j++) {
      int r = (int)(ww[j] >> 16) - rlo;
      if ((unsigned)r < (unsigned)NSUB) {
        int p = atomicAdd(&curb[r], 1);
        esrc_l[p] = (ushort)(ww[j] & 0xFFFFu);
      }
    }
  }
  if (t < ntail) {
    unsigned w = pk[nvec * 4 + t];
    int r = (int)(w >> 16) - rlo;
    if ((unsigned)r < (unsigned)NSUB) {
      int p = atomicAdd(&curb[r], 1);
      esrc_l[p] = (ushort)(w & 0xFFFFu);
    }
  }
  __syncthreads();

  // gather: 4 rounds x 16 nodes; 16 lanes per node, 8 fp8 per lane (uint2).
  const int c = (t & 15) << 3;
#pragma unroll
  for (int rd = 0; rd < 4; rd++) {
    int lr = rd * 16 + (t >> 4);     // local rid 0..63
    int n = (b << 8) + rlo + lr;
    if (n >= N_NODES_C) continue;
    int begin = excl_s[lr];
    int cnt   = hist[lr];
    int end   = begin + cnt;

    float s0 = 0.f, s1 = 0.f, s2 = 0.f, s3 = 0.f;
    float s4 = 0.f, s5 = 0.f, s6 = 0.f, s7 = 0.f;

#define ACCF8(u)                                                   \
    do {                                                           \
      f32x2 p_;                                                    \
      p_ = __builtin_amdgcn_cvt_pk_f32_fp8((u).x, false);          \
      s0 += p_.x; s1 += p_.y;                                      \
      p_ = __builtin_amdgcn_cvt_pk_f32_fp8((u).x, true);           \
      s2 += p_.x; s3 += p_.y;                                      \
      p_ = __builtin_amdgcn_cvt_pk_f32_fp8((u).y, false);          \
      s4 += p_.x; s5 += p_.y;                                      \
      p_ = __builtin_amdgcn_cvt_pk_f32_fp8((u).y, true);           \
      s6 += p_.x; s7 += p_.y;                                      \
    } while (0)

    int i = begin;
    for (; i + 3 < end; i += 4) {
      int e0 = esrc_l[i], e1 = esrc_l[i + 1], e2 = esrc_l[i + 2], e3 = esrc_l[i + 3];
      uint2 a  = *reinterpret_cast<const uint2*>(h8 + (size_t)e0 * DIM_C + c);
      uint2 bb = *reinterpret_cast<const uint2*>(h8 + (size_t)e1 * DIM_C + c);
      uint2 d  = *reinterpret_cast<const uint2*>(h8 + (size_t)e2 * DIM_C + c);
      uint2 f  = *reinterpret_cast<const uint2*>(h8 + (size_t)e3 * DIM_C + c);
      ACCF8(a); ACCF8(bb); ACCF8(d); ACCF8(f);
    }
    for (; i < end; i++) {
      int e0 = esrc_l[i];
      uint2 a = *reinterpret_cast<const uint2*>(h8 + (size_t)e0 * DIM_C + c);
      ACCF8(a);
    }
#undef ACCF8

    float id = 1.0f / (float)max(cnt, 1);   // == 1/deg[n] by construction
    uint4 o;
    o.x = pack2(s0 * id, s1 * id);
    o.y = pack2(s2 * id, s3 * id);
    o.z = pack2(s4 * id, s5 * id);
    o.w = pack2(s6 * id, s7 * id);
    *reinterpret_cast<uint4*>(accb + (size_t)n * DIM_C + c) = o;
  }
}

// --------------------------------------------------------------------------
// K4: fused bf16 MFMA GEMM, K=256 (k<128 from h_bf16, k>=128 from acc_bf16).
// Block = 256 thr (4 waves), 128 rows/block. W staged from pre-cast bf16
// global into padded LDS (uint4 copies).
// Layouts (m89/m91-verified): A[m=lane&15][k=quad*8+j];
// B from W[n][k] with n=lane&15, k=quad*8+j; C/D col=lane&15, row=quad*4+reg.
// --------------------------------------------------------------------------
__global__ __launch_bounds__(256) void sage_gemm_mfma(
    const ushort* __restrict__ hb, const ushort* __restrict__ accb,
    const ushort* __restrict__ wb, const float* __restrict__ bias,
    float* __restrict__ out)
{
  __shared__ ushort Bl[DIM_C][256 + 8];   // 67,584 B
  __shared__ float  bias_l[DIM_C];

  const int t = threadIdx.x;

  for (int idx = t; idx < DIM_C * 16; idx += 256) {
    int n  = idx >> 4;
    int c8 = (idx & 15) << 3;
    uint4 w0 = *reinterpret_cast<const uint4*>(wb + (size_t)n * DIM_C + c8);
    uint4 w1 = *reinterpret_cast<const uint4*>(wb + (size_t)(DIM_C + n) * DIM_C + c8);
    *reinterpret_cast<uint4*>(&Bl[n][c8])       = w0;
    *reinterpret_cast<uint4*>(&Bl[n][128 + c8]) = w1;
  }
  if (t < DIM_C) bias_l[t] = bias[t];
  __syncthreads();

  const int lane = t & 63;
  const int w    = t >> 6;
  const int am   = lane & 15;
  const int q    = lane >> 4;
  const int mb   = blockIdx.x * 128;
  const int m0   = mb + w * 16;        // row-tile 0
  const int m1   = mb + 64 + w * 16;   // row-tile 1

  int r0 = m0 + am; if (r0 >= N_NODES_C) r0 = N_NODES_C - 1;
  int r1 = m1 + am; if (r1 >= N_NODES_C) r1 = N_NODES_C - 1;
  const ushort* aph0 = hb   + (size_t)r0 * DIM_C + q * 8;
  const ushort* apa0 = accb + (size_t)r0 * DIM_C + q * 8;
  const ushort* aph1 = hb   + (size_t)r1 * DIM_C + q * 8;
  const ushort* apa1 = accb + (size_t)r1 * DIM_C + q * 8;

  f32x4 acc[2][8];
#pragma unroll
  for (int i = 0; i < 2; i++)
#pragma unroll
    for (int nt = 0; nt < 8; nt++) acc[i][nt] = (f32x4){0.f, 0.f, 0.f, 0.f};

#pragma unroll
  for (int ks = 0; ks < 4; ks++) {
    short8 a0 = *reinterpret_cast<const short8*>(aph0 + ks * 32);
    short8 a1 = *reinterpret_cast<const short8*>(aph1 + ks * 32);
#pragma unroll
    for (int nt = 0; nt < 8; nt++) {
      short8 bf = *reinterpret_cast<const short8*>(&Bl[nt * 16 + am][ks * 32 + q * 8]);
      acc[0][nt] = __builtin_amdgcn_mfma_f32_16x16x32_bf16(a0, bf, acc[0][nt], 0, 0, 0);
      acc[1][nt] = __builtin_amdgcn_mfma_f32_16x16x32_bf16(a1, bf, acc[1][nt], 0, 0, 0);
    }
  }
#pragma unroll
  for (int ks = 0; ks < 4; ks++) {
    short8 a0 = *reinterpret_cast<const short8*>(apa0 + ks * 32);
    short8 a1 = *reinterpret_cast<const short8*>(apa1 + ks * 32);
#pragma unroll
    for (int nt = 0; nt < 8; nt++) {
      short8 bf = *reinterpret_cast<const short8*>(&Bl[nt * 16 + am][128 + ks * 32 + q * 8]);
      acc[0][nt] = __builtin_amdgcn_mfma_f32_16x16x32_bf16(a0, bf, acc[0][nt], 0, 0, 0);
      acc[1][nt] = __builtin_amdgcn_mfma_f32_16x16x32_bf16(a1, bf, acc[1][nt], 0, 0, 0);
    }
  }

#pragma unroll
  for (int i = 0; i < 2; i++) {
    int mt = (i == 0) ? m0 : m1;
#pragma unroll
    for (int nt = 0; nt < 8; nt++) {
      int col = nt * 16 + am;
      float bv = bias_l[col];
#pragma unroll
      for (int rr = 0; rr < 4; rr++) {
        int row = mt + q * 4 + rr;
        if (row < N_NODES_C) {
          float v = acc[i][nt][rr] + bv;
          out[(size_t)row * DIM_C + col] = fmaxf(v, 0.f);
        }
      }
    }
  }
}

// --------------------------------------------------------------------------
extern "C" void kernel_launch(void* const* d_in, const int* in_sizes, int n_in,
                              void* d_out, int out_size, void* d_ws, size_t ws_size,
                              hipStream_t stream) {
  const float* h      = (const float*)d_in[0];
  const int*   src    = (const int*)d_in[1];
  const int*   dst    = (const int*)d_in[2];
  const float* Wself  = (const float*)d_in[4];
  const float* Wneigh = (const float*)d_in[5];
  const float* bias   = (const float*)d_in[6];
  float*       out    = (float*)d_out;

  char* ws = (char*)d_ws;
  ushort*        hb     = (ushort*)(ws + OFF_HB);
  ushort*        accb   = (ushort*)(ws + OFF_ACC);
  unsigned*      packed = (unsigned*)(ws + OFF_PK);
  int*           gcur   = (int*)(ws + OFF_GC);
  ushort*        wb     = (ushort*)(ws + OFF_WB);
  unsigned char* h8     = (unsigned char*)(ws + OFF_H8);

  // Zero the 196 bucket cursors only (784 B); all else fully overwritten.
  hipMemsetAsync(gcur, 0, NBKT * sizeof(int), stream);

  sage_cast_bucket<<<NB_SCAT + NB_WCAST + NB_CASTK, 1024, 0, stream>>>(
      h, hb, h8, Wself, Wneigh, wb, src, dst, gcur, packed);
  sage_csr_gather <<<NBKT * SUBS, 256, 0, stream>>>(packed, gcur, h8, accb);
  sage_gemm_mfma  <<<(N_NODES_C + 127) / 128, 256, 0, stream>>>(hb, accb, wb,
                                                                bias, out);
}

// Round 13
// 126.696 us; speedup vs baseline: 1.1070x; 1.0597x over previous
//
#include <hip/hip_runtime.h>

// GraphSAGE layer: out = relu(h @ Ws^T + (scatter_mean(h,src,dst)) @ Wn^T + b)
// N=50000, E=800000, dim 128.
// R13: gather 8 lanes/node x uint4 (16B) fp8 loads. R12 showed byte-halving
//      bought only ~4us => gather is VMEM-issue-bound (12.8M load insts).
//      This halves inst count to 6.4M (minimum at 16B/lane). 16 f32
//      accumulators/lane. Single-variable experiment on the issue theory.
constexpr int N_NODES_C = 50000;
constexpr int N_EDGES_C = 800000;
constexpr int DIM_C     = 128;

constexpr int NBKT  = 196;    // (50000+255)>>8
constexpr int CAP   = 8192;   // bucket capacity; mean fill 4096, sd ~64
constexpr int EPB_S = 8192;   // edges per scatter block
constexpr int NB_SCAT  = 98;  // (800000+8191)/8192
constexpr int NB_WCAST = 2;   // W-cast blocks: one per matrix
constexpr int NB_CASTK = 391; // h-cast blocks: 1024 thr x 16 elems, guarded

constexpr int SUBS    = 4;    // csr_gather sub-blocks per bucket
constexpr int NSUB    = 64;   // nodes per sub-block
constexpr int CAP_SUB = 2048; // sub-block edge capacity; mean 1024, sd ~32

typedef __attribute__((ext_vector_type(8))) short short8;  // 8 bf16, 4 VGPRs
typedef __attribute__((ext_vector_type(4))) float f32x4;
typedef __attribute__((ext_vector_type(2))) float f32x2;

// Workspace layout (bytes), ~38.7 MB used:
constexpr size_t OFF_HB   = 0;                                   // ushort[N][128]
constexpr size_t OFF_ACC  = (size_t)N_NODES_C * DIM_C * 2;       // 12,800,000
constexpr size_t OFF_PK   = OFF_ACC + (size_t)N_NODES_C * DIM_C * 2;  // 25,600,000
constexpr size_t OFF_GC   = OFF_PK + (size_t)NBKT * CAP * 4;     // 32,022,528
constexpr size_t OFF_WB   = OFF_GC + 1024;                       // ushort[2][128][128]
constexpr size_t OFF_H8   = OFF_WB + 2 * DIM_C * DIM_C * 2;      // uchar[N][128] fp8

// round-to-nearest-even f32 -> bf16 bits (finite inputs only)
static __device__ __forceinline__ ushort f2bf(float f) {
  unsigned u = __float_as_uint(f);
  return (ushort)((u + 0x7FFFu + ((u >> 16) & 1u)) >> 16);
}
static __device__ __forceinline__ unsigned pack2(float a, float b) {
  return (unsigned)f2bf(a) | ((unsigned)f2bf(b) << 16);
}
// 4 floats -> 4 packed OCP e4m3 bytes (HW cvt, RNE)
static __device__ __forceinline__ unsigned pk_fp8x4(float4 a) {
  unsigned u = __builtin_amdgcn_cvt_pk_fp8_f32(a.x, a.y, 0u, false);
  return __builtin_amdgcn_cvt_pk_fp8_f32(a.z, a.w, u, true);
}

// --------------------------------------------------------------------------
// K_A: fused bucket scatter + cast(W) + cast(h -> bf16 AND fp8).
// Scatter block (8192 edges): LDS hist over 196 buckets -> wave-0 scan ->
// one global atomicAdd per nonzero bin (bulk reserve, ~19k total) -> LDS
// counting sort -> per-run coalesced burst write-out.
// --------------------------------------------------------------------------
__global__ __launch_bounds__(1024) void sage_cast_bucket(
    const float* __restrict__ h, ushort* __restrict__ hb,
    unsigned char* __restrict__ h8,
    const float* __restrict__ Wself, const float* __restrict__ Wneigh,
    ushort* __restrict__ wb,
    const int* __restrict__ src, const int* __restrict__ dst,
    int* __restrict__ gcur, unsigned* __restrict__ packed)
{
  const int b = blockIdx.x;
  const int t = threadIdx.x;
  if (b >= NB_SCAT) {
    if (b < NB_SCAT + NB_WCAST) {
      int m = b - NB_SCAT;                    // 0: Wself, 1: Wneigh
      const float* sp = m ? Wneigh : Wself;
      ushort* dp = wb + (size_t)m * DIM_C * DIM_C;
      size_t i = (size_t)t * 16;              // 1024*16 = 16384 exactly
      float4 a0 = *reinterpret_cast<const float4*>(sp + i);
      float4 a1 = *reinterpret_cast<const float4*>(sp + i + 4);
      float4 a2 = *reinterpret_cast<const float4*>(sp + i + 8);
      float4 a3 = *reinterpret_cast<const float4*>(sp + i + 12);
      uint4 o0, o1;
      o0.x = pack2(a0.x, a0.y); o0.y = pack2(a0.z, a0.w);
      o0.z = pack2(a1.x, a1.y); o0.w = pack2(a1.z, a1.w);
      o1.x = pack2(a2.x, a2.y); o1.y = pack2(a2.z, a2.w);
      o1.z = pack2(a3.x, a3.y); o1.w = pack2(a3.z, a3.w);
      *reinterpret_cast<uint4*>(dp + i)     = o0;
      *reinterpret_cast<uint4*>(dp + i + 8) = o1;
    } else {
      int tid = (b - NB_SCAT - NB_WCAST) * 1024 + t;
      if (tid >= 400000) return;              // 400000*16 = 6.4M elems
      size_t i = (size_t)tid * 16;
      float4 a0 = *reinterpret_cast<const float4*>(h + i);
      float4 a1 = *reinterpret_cast<const float4*>(h + i + 4);
      float4 a2 = *reinterpret_cast<const float4*>(h + i + 8);
      float4 a3 = *reinterpret_cast<const float4*>(h + i + 12);
      uint4 o0, o1;
      o0.x = pack2(a0.x, a0.y); o0.y = pack2(a0.z, a0.w);
      o0.z = pack2(a1.x, a1.y); o0.w = pack2(a1.z, a1.w);
      o1.x = pack2(a2.x, a2.y); o1.y = pack2(a2.z, a2.w);
      o1.z = pack2(a3.x, a3.y); o1.w = pack2(a3.z, a3.w);
      *reinterpret_cast<uint4*>(hb + i)     = o0;
      *reinterpret_cast<uint4*>(hb + i + 8) = o1;
      uint4 q;                                 // 16 fp8 bytes
      q.x = pk_fp8x4(a0); q.y = pk_fp8x4(a1);
      q.z = pk_fp8x4(a2); q.w = pk_fp8x4(a3);
      *reinterpret_cast<uint4*>(h8 + i) = q;
    }
    return;
  }

  __shared__ int      bh[256];       // per-bucket count (padded for scan)
  __shared__ int      excl[256];
  __shared__ int      curb[NBKT];
  __shared__ int      bofsG[NBKT];   // reserved base within bucket region
  __shared__ unsigned sorted[EPB_S]; // 32 KB

  const int e0 = b * EPB_S + t * 8;
  const bool l0 = (e0     < N_EDGES_C);      // E%4==0: int4 valid when base<E
  const bool l1 = (e0 + 4 < N_EDGES_C);

  if (t < 256) bh[t] = 0;
  __syncthreads();

  int4 da, db, sa, sb;
  if (l0) {
    da = *reinterpret_cast<const int4*>(dst + e0);
    sa = *reinterpret_cast<const int4*>(src + e0);
    atomicAdd(&bh[da.x >> 8], 1); atomicAdd(&bh[da.y >> 8], 1);
    atomicAdd(&bh[da.z >> 8], 1); atomicAdd(&bh[da.w >> 8], 1);
  }
  if (l1) {
    db = *reinterpret_cast<const int4*>(dst + e0 + 4);
    sb = *reinterpret_cast<const int4*>(src + e0 + 4);
    atomicAdd(&bh[db.x >> 8], 1); atomicAdd(&bh[db.y >> 8], 1);
    atomicAdd(&bh[db.z >> 8], 1); atomicAdd(&bh[db.w >> 8], 1);
  }
  __syncthreads();

  // exclusive scan of bh[256] by wave 0 (4 bins/lane)
  if (t < 64) {
    int base = t * 4;
    int h0 = bh[base], h1 = bh[base + 1], h2 = bh[base + 2], h3 = bh[base + 3];
    int s = h0 + h1 + h2 + h3;
    int x = s;
#pragma unroll
    for (int d = 1; d < 64; d <<= 1) {
      int y = __shfl_up(x, d, 64);
      if (t >= d) x += y;
    }
    int ex = x - s;
    excl[base]     = ex;
    excl[base + 1] = ex + h0;
    excl[base + 2] = ex + h0 + h1;
    excl[base + 3] = ex + h0 + h1 + h2;
  }
  __syncthreads();

  if (t < NBKT) {
    curb[t]  = excl[t];
    bofsG[t] = (bh[t] > 0) ? atomicAdd(&gcur[t], bh[t]) : 0;
  }
  __syncthreads();

#define PLACE(dd, ss)                                            \
  do {                                                           \
    int p_ = atomicAdd(&curb[(dd) >> 8], 1);                     \
    sorted[p_] = ((unsigned)((dd) & 255) << 16) | (unsigned)(ss);\
  } while (0)
  if (l0) { PLACE(da.x, sa.x); PLACE(da.y, sa.y); PLACE(da.z, sa.z); PLACE(da.w, sa.w); }
  if (l1) { PLACE(db.x, sb.x); PLACE(db.y, sb.y); PLACE(db.z, sb.z); PLACE(db.w, sb.w); }
#undef PLACE
  __syncthreads();

  // coalesced burst write-out: wave w owns buckets w, w+16, ...
  const int w    = t >> 6;
  const int lane = t & 63;
  for (int k = w; k < NBKT; k += 16) {
    int len = bh[k];
    int gb  = bofsG[k];
    if (gb + len > CAP) len = CAP - gb;      // statistically unreachable
    int lb  = excl[k];
    unsigned* outp = packed + (size_t)k * CAP + gb;
    for (int off = lane; off < len; off += 64)
      outp[off] = sorted[lb + off];
  }
}

// --------------------------------------------------------------------------
// K_B: per-sub-bucket counting sort + gather-mean, fp8 rows (128B/row).
// Block (bucket b, sub s) owns node-ids rid in [s*64, s*64+64). 784x256.
// Gather: 8 lanes/node x 16 fp8 (uint4, 16B) per lane -> 6.4M total VMEM
// insts (half of R12); 16 f32 accumulators/lane; HW cvt; bf16 mean out.
// 1/deg from hist (== input deg by construction).
// --------------------------------------------------------------------------
__global__ __launch_bounds__(256) void sage_csr_gather(
    const unsigned* __restrict__ packed, const int* __restrict__ gcur,
    const unsigned char* __restrict__ h8, ushort* __restrict__ accb)
{
  __shared__ int    hist[NSUB];
  __shared__ int    excl_s[NSUB];
  __shared__ int    curb[NSUB];
  __shared__ ushort esrc_l[CAP_SUB];   // 4 KB

  const int b   = blockIdx.x >> 2;     // bucket
  const int sub = blockIdx.x & 3;
  const int rlo = sub * NSUB;
  const int t = threadIdx.x;
  const int count = min(gcur[b], CAP);
  const unsigned* pk = packed + (size_t)b * CAP;
  const int nvec = count >> 2;
  const int ntail = count & 3;

  if (t < NSUB) hist[t] = 0;
  __syncthreads();

  // pass 1: histogram of our rid range (vectorized scan, L2-hot)
  for (int g = t; g < nvec; g += 256) {
    uint4 w4 = *reinterpret_cast<const uint4*>(pk + g * 4);
    int r;
    r = (int)(w4.x >> 16) - rlo; if ((unsigned)r < (unsigned)NSUB) atomicAdd(&hist[r], 1);
    r = (int)(w4.y >> 16) - rlo; if ((unsigned)r < (unsigned)NSUB) atomicAdd(&hist[r], 1);
    r = (int)(w4.z >> 16) - rlo; if ((unsigned)r < (unsigned)NSUB) atomicAdd(&hist[r], 1);
    r = (int)(w4.w >> 16) - rlo; if ((unsigned)r < (unsigned)NSUB) atomicAdd(&hist[r], 1);
  }
  if (t < ntail) {
    int r = (int)(pk[nvec * 4 + t] >> 16) - rlo;
    if ((unsigned)r < (unsigned)NSUB) atomicAdd(&hist[r], 1);
  }
  __syncthreads();

  // exclusive scan of hist[64] by wave 0 (1 bin per lane)
  if (t < 64) {
    int v = hist[t];
    int x = v;
#pragma unroll
    for (int d = 1; d < 64; d <<= 1) {
      int y = __shfl_up(x, d, 64);
      if (t >= d) x += y;
    }
    excl_s[t] = x - v;
    curb[t]   = x - v;
  }
  __syncthreads();

  // pass 2: filtered placement
  for (int g = t; g < nvec; g += 256) {
    uint4 w4 = *reinterpret_cast<const uint4*>(pk + g * 4);
    unsigned ww[4] = {w4.x, w4.y, w4.z, w4.w};
#pragma unroll
    for (int j = 0; j < 4; j++) {
      int r = (int)(ww[j] >> 16) - rlo;
      if ((unsigned)r < (unsigned)NSUB) {
        int p = atomicAdd(&curb[r], 1);
        esrc_l[p] = (ushort)(ww[j] & 0xFFFFu);
      }
    }
  }
  if (t < ntail) {
    unsigned w = pk[nvec * 4 + t];
    int r = (int)(w >> 16) - rlo;
    if ((unsigned)r < (unsigned)NSUB) {
      int p = atomicAdd(&curb[r], 1);
      esrc_l[p] = (ushort)(w & 0xFFFFu);
    }
  }
  __syncthreads();

  // gather: 2 rounds x 32 nodes; 8 lanes per node, 16 fp8 per lane (uint4).
  const int c = (t & 7) << 4;
#pragma unroll
  for (int rd = 0; rd < 2; rd++) {
    int lr = rd * 32 + (t >> 3);     // local rid 0..63
    int n = (b << 8) + rlo + lr;
    if (n >= N_NODES_C) continue;
    int begin = excl_s[lr];
    int cnt   = hist[lr];
    int end   = begin + cnt;

    float s[16];
#pragma unroll
    for (int j = 0; j < 16; j++) s[j] = 0.f;

#define ACCD(wd, o)                                                \
    do {                                                           \
      f32x2 p_;                                                    \
      p_ = __builtin_amdgcn_cvt_pk_f32_fp8((wd), false);           \
      s[(o)]     += p_.x; s[(o) + 1] += p_.y;                      \
      p_ = __builtin_amdgcn_cvt_pk_f32_fp8((wd), true);            \
      s[(o) + 2] += p_.x; s[(o) + 3] += p_.y;                      \
    } while (0)
#define ACC16(u)                                                   \
    do { ACCD((u).x, 0); ACCD((u).y, 4); ACCD((u).z, 8); ACCD((u).w, 12); } while (0)

    int i = begin;
    for (; i + 3 < end; i += 4) {
      int e0 = esrc_l[i], e1 = esrc_l[i + 1], e2 = esrc_l[i + 2], e3 = esrc_l[i + 3];
      uint4 a  = *reinterpret_cast<const uint4*>(h8 + (size_t)e0 * DIM_C + c);
      uint4 bb = *reinterpret_cast<const uint4*>(h8 + (size_t)e1 * DIM_C + c);
      uint4 d  = *reinterpret_cast<const uint4*>(h8 + (size_t)e2 * DIM_C + c);
      uint4 f  = *reinterpret_cast<const uint4*>(h8 + (size_t)e3 * DIM_C + c);
      ACC16(a); ACC16(bb); ACC16(d); ACC16(f);
    }
    for (; i < end; i++) {
      int e0 = esrc_l[i];
      uint4 a = *reinterpret_cast<const uint4*>(h8 + (size_t)e0 * DIM_C + c);
      ACC16(a);
    }
#undef ACC16
#undef ACCD

    float id = 1.0f / (float)max(cnt, 1);   // == 1/deg[n] by construction
    uint4 o0, o1;
    o0.x = pack2(s[0]  * id, s[1]  * id);
    o0.y = pack2(s[2]  * id, s[3]  * id);
    o0.z = pack2(s[4]  * id, s[5]  * id);
    o0.w = pack2(s[6]  * id, s[7]  * id);
    o1.x = pack2(s[8]  * id, s[9]  * id);
    o1.y = pack2(s[10] * id, s[11] * id);
    o1.z = pack2(s[12] * id, s[13] * id);
    o1.w = pack2(s[14] * id, s[15] * id);
    *reinterpret_cast<uint4*>(accb + (size_t)n * DIM_C + c)     = o0;
    *reinterpret_cast<uint4*>(accb + (size_t)n * DIM_C + c + 8) = o1;
  }
}

// --------------------------------------------------------------------------
// K4: fused bf16 MFMA GEMM, K=256 (k<128 from h_bf16, k>=128 from acc_bf16).
// Block = 256 thr (4 waves), 128 rows/block. W staged from pre-cast bf16
// global into padded LDS (uint4 copies).
// Layouts (m89/m91-verified): A[m=lane&15][k=quad*8+j];
// B from W[n][k] with n=lane&15, k=quad*8+j; C/D col=lane&15, row=quad*4+reg.
// --------------------------------------------------------------------------
__global__ __launch_bounds__(256) void sage_gemm_mfma(
    const ushort* __restrict__ hb, const ushort* __restrict__ accb,
    const ushort* __restrict__ wb, const float* __restrict__ bias,
    float* __restrict__ out)
{
  __shared__ ushort Bl[DIM_C][256 + 8];   // 67,584 B
  __shared__ float  bias_l[DIM_C];

  const int t = threadIdx.x;

  for (int idx = t; idx < DIM_C * 16; idx += 256) {
    int n  = idx >> 4;
    int c8 = (idx & 15) << 3;
    uint4 w0 = *reinterpret_cast<const uint4*>(wb + (size_t)n * DIM_C + c8);
    uint4 w1 = *reinterpret_cast<const uint4*>(wb + (size_t)(DIM_C + n) * DIM_C + c8);
    *reinterpret_cast<uint4*>(&Bl[n][c8])       = w0;
    *reinterpret_cast<uint4*>(&Bl[n][128 + c8]) = w1;
  }
  if (t < DIM_C) bias_l[t] = bias[t];
  __syncthreads();

  const int lane = t & 63;
  const int w    = t >> 6;
  const int am   = lane & 15;
  const int q    = lane >> 4;
  const int mb   = blockIdx.x * 128;
  const int m0   = mb + w * 16;        // row-tile 0
  const int m1   = mb + 64 + w * 16;   // row-tile 1

  int r0 = m0 + am; if (r0 >= N_NODES_C) r0 = N_NODES_C - 1;
  int r1 = m1 + am; if (r1 >= N_NODES_C) r1 = N_NODES_C - 1;
  const ushort* aph0 = hb   + (size_t)r0 * DIM_C + q * 8;
  const ushort* apa0 = accb + (size_t)r0 * DIM_C + q * 8;
  const ushort* aph1 = hb   + (size_t)r1 * DIM_C + q * 8;
  const ushort* apa1 = accb + (size_t)r1 * DIM_C + q * 8;

  f32x4 acc[2][8];
#pragma unroll
  for (int i = 0; i < 2; i++)
#pragma unroll
    for (int nt = 0; nt < 8; nt++) acc[i][nt] = (f32x4){0.f, 0.f, 0.f, 0.f};

#pragma unroll
  for (int ks = 0; ks < 4; ks++) {
    short8 a0 = *reinterpret_cast<const short8*>(aph0 + ks * 32);
    short8 a1 = *reinterpret_cast<const short8*>(aph1 + ks * 32);
#pragma unroll
    for (int nt = 0; nt < 8; nt++) {
      short8 bf = *reinterpret_cast<const short8*>(&Bl[nt * 16 + am][ks * 32 + q * 8]);
      acc[0][nt] = __builtin_amdgcn_mfma_f32_16x16x32_bf16(a0, bf, acc[0][nt], 0, 0, 0);
      acc[1][nt] = __builtin_amdgcn_mfma_f32_16x16x32_bf16(a1, bf, acc[1][nt], 0, 0, 0);
    }
  }
#pragma unroll
  for (int ks = 0; ks < 4; ks++) {
    short8 a0 = *reinterpret_cast<const short8*>(apa0 + ks * 32);
    short8 a1 = *reinterpret_cast<const short8*>(apa1 + ks * 32);
#pragma unroll
    for (int nt = 0; nt < 8; nt++) {
      short8 bf = *reinterpret_cast<const short8*>(&Bl[nt * 16 + am][128 + ks * 32 + q * 8]);
      acc[0][nt] = __builtin_amdgcn_mfma_f32_16x16x32_bf16(a0, bf, acc[0][nt], 0, 0, 0);
      acc[1][nt] = __builtin_amdgcn_mfma_f32_16x16x32_bf16(a1, bf, acc[1][nt], 0, 0, 0);
    }
  }

#pragma unroll
  for (int i = 0; i < 2; i++) {
    int mt = (i == 0) ? m0 : m1;
#pragma unroll
    for (int nt = 0; nt < 8; nt++) {
      int col = nt * 16 + am;
      float bv = bias_l[col];
#pragma unroll
      for (int rr = 0; rr < 4; rr++) {
        int row = mt + q * 4 + rr;
        if (row < N_NODES_C) {
          float v = acc[i][nt][rr] + bv;
          out[(size_t)row * DIM_C + col] = fmaxf(v, 0.f);
        }
      }
    }
  }
}

// --------------------------------------------------------------------------
extern "C" void kernel_launch(void* const* d_in, const int* in_sizes, int n_in,
                              void* d_out, int out_size, void* d_ws, size_t ws_size,
                              hipStream_t stream) {
  const float* h      = (const float*)d_in[0];
  const int*   src    = (const int*)d_in[1];
  const int*   dst    = (const int*)d_in[2];
  const float* Wself  = (const float*)d_in[4];
  const float* Wneigh = (const float*)d_in[5];
  const float* bias   = (const float*)d_in[6];
  float*       out    = (float*)d_out;

  char* ws = (char*)d_ws;
  ushort*        hb     = (ushort*)(ws + OFF_HB);
  ushort*        accb   = (ushort*)(ws + OFF_ACC);
  unsigned*      packed = (unsigned*)(ws + OFF_PK);
  int*           gcur   = (int*)(ws + OFF_GC);
  ushort*        wb     = (ushort*)(ws + OFF_WB);
  unsigned char* h8     = (unsigned char*)(ws + OFF_H8);

  // Zero the 196 bucket cursors only (784 B); all else fully overwritten.
  hipMemsetAsync(gcur, 0, NBKT * sizeof(int), stream);

  sage_cast_bucket<<<NB_SCAT + NB_WCAST + NB_CASTK, 1024, 0, stream>>>(
      h, hb, h8, Wself, Wneigh, wb, src, dst, gcur, packed);
  sage_csr_gather <<<NBKT * SUBS, 256, 0, stream>>>(packed, gcur, h8, accb);
  sage_gemm_mfma  <<<(N_NODES_C + 127) / 128, 256, 0, stream>>>(hb, accb, wb,
                                                                bias, out);
}